// Round 2
// baseline (406.021 us; speedup 1.0000x reference)
//
#include <hip/hip_runtime.h>
#include <hip/hip_bf16.h>

typedef unsigned short u16;
typedef __attribute__((ext_vector_type(8))) short short8;
typedef __attribute__((ext_vector_type(4))) float f32x4;

#define B_ 8
#define V_ 64
#define T_ 256
#define T1_ 257
#define D_ 256
#define H_ 8
#define DH_ 32

__device__ __forceinline__ u16 f2bf(float f){
  union { float f; unsigned int u; } v; v.f = f;
  unsigned int u = v.u;
  return (u16)((u + 0x7fffu + ((u >> 16) & 1u)) >> 16);
}

// ---------------- kernel 1: LN stats + masked xn-sum + weight conversion ----------------
// grid 640, block 512. Blocks 512..639: convert Wv/Wp to bf16 (one elem of each
// per thread). Blocks 0..511: one block per bv, 8 waves; each half-wave owns one
// t (8 floats/lane, 5-level butterfly in 32 lanes). Block writes xsum directly:
// no atomics, no zeroing pass.
__global__ void k1_ln(const float* __restrict__ x, const int* __restrict__ mask,
                      const float* __restrict__ lnw, const float* __restrict__ lnb,
                      const float* __restrict__ wqkv, const float* __restrict__ wproj,
                      float* __restrict__ musig, float* __restrict__ xsum,
                      u16* __restrict__ wv, u16* __restrict__ wp){
  if (blockIdx.x >= 512){
    int j = (blockIdx.x - 512) * 512 + threadIdx.x;   // 0..65535
    wv[j] = f2bf(wqkv[131072 + j]);
    wp[j] = f2bf(wproj[j]);
    return;
  }
  int bv = blockIdx.x;
  int tid = threadIdx.x;
  int lane = tid & 63, wid = tid >> 6;
  int half = lane >> 5, l32 = lane & 31;
  int c8 = l32 * 8;
  __shared__ float xsred[8][512];
  float4 w0 = *(const float4*)&lnw[c8], w1 = *(const float4*)&lnw[c8 + 4];
  float4 b0 = *(const float4*)&lnb[c8], b1 = *(const float4*)&lnb[c8 + 4];
  float xs[8];
  #pragma unroll
  for (int j = 0; j < 8; ++j) xs[j] = 0.f;
  for (int p = wid; p < 129; p += 8){
    int t = p * 2 + half;
    bool valid = (t < T1_);
    float4 a0 = {0.f,0.f,0.f,0.f}, a1 = {0.f,0.f,0.f,0.f};
    if (valid){
      const float* gp = &x[((long)bv * T1_ + t) * D_ + c8];
      a0 = *(const float4*)gp; a1 = *(const float4*)(gp + 4);
    }
    float s  = a0.x + a0.y + a0.z + a0.w + a1.x + a1.y + a1.z + a1.w;
    float s2 = a0.x*a0.x + a0.y*a0.y + a0.z*a0.z + a0.w*a0.w
             + a1.x*a1.x + a1.y*a1.y + a1.z*a1.z + a1.w*a1.w;
    #pragma unroll
    for (int off = 1; off < 32; off <<= 1){
      s  += __shfl_xor(s,  off, 64);
      s2 += __shfl_xor(s2, off, 64);
    }
    float mu   = s * (1.f / 256.f);
    float var  = s2 * (1.f / 256.f) - mu * mu;
    float rstd = rsqrtf(var + 1e-5f);
    if (valid){
      if (l32 == 0){
        musig[((long)bv * T1_ + t) * 2]     = mu;
        musig[((long)bv * T1_ + t) * 2 + 1] = rstd;
      }
      int m = (t == 0) ? 1 : mask[bv * T_ + (t - 1)];
      if (m){
        xs[0] += (a0.x - mu) * rstd * w0.x + b0.x;
        xs[1] += (a0.y - mu) * rstd * w0.y + b0.y;
        xs[2] += (a0.z - mu) * rstd * w0.z + b0.z;
        xs[3] += (a0.w - mu) * rstd * w0.w + b0.w;
        xs[4] += (a1.x - mu) * rstd * w1.x + b1.x;
        xs[5] += (a1.y - mu) * rstd * w1.y + b1.y;
        xs[6] += (a1.z - mu) * rstd * w1.z + b1.z;
        xs[7] += (a1.w - mu) * rstd * w1.w + b1.w;
      }
    }
  }
  #pragma unroll
  for (int j = 0; j < 8; ++j) xsred[wid][half * 256 + c8 + j] = xs[j];
  __syncthreads();
  if (tid < 256){
    float r = 0.f;
    #pragma unroll
    for (int w2 = 0; w2 < 8; ++w2) r += xsred[w2][tid] + xsred[w2][256 + tid];
    xsum[bv * D_ + tid] = r;
  }
}

// ---------------- kernel 2a: q,k projections (tiny) ----------------
__global__ void k2a_qk(const float* __restrict__ x, const int* __restrict__ mask,
                       const float* __restrict__ lnw, const float* __restrict__ lnb,
                       const float* __restrict__ wqkv,
                       const float* __restrict__ musig, const float* __restrict__ xsum,
                       float* __restrict__ qout, float* __restrict__ kout){
  int bv = blockIdx.x, tid = threadIdx.x;
  int lane = tid & 63, wid = tid >> 6;
  __shared__ __align__(16) float xn0[D_];
  __shared__ __align__(16) float xs[D_];
  __shared__ float redc[4];
  int s = mask[bv * T_ + tid];
  #pragma unroll
  for (int off = 32; off >= 1; off >>= 1) s += __shfl_down(s, off, 64);
  if (lane == 0) redc[wid] = (float)s;
  __syncthreads();
  float cnt = 1.f + redc[0] + redc[1] + redc[2] + redc[3];
  float mu = musig[((long)bv * T1_) * 2], rstd = musig[((long)bv * T1_) * 2 + 1];
  xn0[tid] = (x[((long)bv * T1_) * D_ + tid] - mu) * rstd * lnw[tid] + lnb[tid];
  xs[tid]  = xsum[bv * D_ + tid] * (1.f / cnt);
  __syncthreads();
  float4 xq = *(const float4*)&xn0[lane * 4];
  float4 xk = *(const float4*)&xs[lane * 4];
  int e0 = (blockIdx.y * 4 + wid) * 16;
  for (int i = 0; i < 16; ++i){
    int e = e0 + i;
    float4 wq4 = *(const float4*)&wqkv[(long)e * D_ + lane * 4];
    float4 wk4 = *(const float4*)&wqkv[(long)(256 + e) * D_ + lane * 4];
    float sq = xq.x*wq4.x + xq.y*wq4.y + xq.z*wq4.z + xq.w*wq4.w;
    float sk = xk.x*wk4.x + xk.y*wk4.y + xk.z*wk4.z + xk.w*wk4.w;
    #pragma unroll
    for (int off = 32; off >= 1; off >>= 1){
      sq += __shfl_down(sq, off, 64);
      sk += __shfl_down(sk, off, 64);
    }
    if (lane == 0){ qout[bv * D_ + e] = sq; kout[bv * D_ + e] = sk; }
  }
}

// ---------------- kernel 2b: 64x64 attention per (b,h) ----------------
// grid (64,4), 256 threads: lane = key index; y-block handles 4 q-row groups.
__global__ void k2b_attn(const float* __restrict__ q, const float* __restrict__ k,
                         u16* __restrict__ attn){
  int bh = blockIdx.x; int b = bh >> 3, h = bh & 7;
  int tid = threadIdx.x;
  int lane = tid & 63, wid = tid >> 6;
  __shared__ float qs[64][33], ks[64][33];
  #pragma unroll
  for (int j = 0; j < 2; ++j){
    int i4 = tid * 2 + j;
    int r = i4 >> 3, c4 = (i4 & 7) * 4;
    float4 vq = *(const float4*)&q[((long)(b * V_ + r)) * D_ + h * DH_ + c4];
    float4 vk = *(const float4*)&k[((long)(b * V_ + r)) * D_ + h * DH_ + c4];
    qs[r][c4] = vq.x; qs[r][c4+1] = vq.y; qs[r][c4+2] = vq.z; qs[r][c4+3] = vq.w;
    ks[r][c4] = vk.x; ks[r][c4+1] = vk.y; ks[r][c4+2] = vk.z; ks[r][c4+3] = vk.w;
  }
  __syncthreads();
  const float scale = 0.17677669529663687f;  // 1/sqrt(32)
  for (int i = blockIdx.y * 4; i < blockIdx.y * 4 + 4; ++i){
    int qr = i * 4 + wid;
    float a = 0.f;
    #pragma unroll
    for (int d = 0; d < DH_; ++d) a += qs[qr][d] * ks[lane][d];
    a *= scale;
    float mx = a;
    #pragma unroll
    for (int off = 1; off < 64; off <<= 1) mx = fmaxf(mx, __shfl_xor(mx, off, 64));
    float e = __expf(a - mx);
    float sum = e;
    #pragma unroll
    for (int off = 1; off < 64; off <<= 1) sum += __shfl_xor(sum, off, 64);
    attn[((long)bh * 64 + qr) * 64 + lane] = f2bf(e * (1.f / sum));
  }
}

// ---------------- kernel 3: fused LN -> V-proj -> attn-mix -> out-proj -> residual ----------------
// VT LDS buffer eliminated: wave w's GEMM1 output (vf cols [32w,32w+32)) is
// exactly what its own head's mix needs as B-operand. C-frag -> B-frag
// conversion done in registers: bf16-pack acc1 then 32 __shfl redistribute
// across lq quadrants. LDS ~37 KB -> 3 blocks/CU (launch_bounds 512,6).
__global__ __launch_bounds__(512, 6) void k3_main(
    const float* __restrict__ x, const float* __restrict__ lnw, const float* __restrict__ lnb,
    const float* __restrict__ bproj, const float* __restrict__ musig,
    const u16* __restrict__ wv, const u16* __restrict__ wp,
    const u16* __restrict__ attn, float* __restrict__ out){
  constexpr int XS = 264;   // row stride (bf16 elems) for Xs/Ms
  __shared__ __align__(16) u16 Xs[64 * XS];    // xn slice; reused as mix (Ms)
  __shared__ float lnw_s[D_], lnb_s[D_], bp_s[D_];
  __shared__ float ms_s[V_ * 2];

  int bt = blockIdx.x; int b = bt / T1_, t = bt % T1_;
  int tid = threadIdx.x;
  int w = tid >> 6, lane = tid & 63, lm = lane & 15, lq = lane >> 4;
  int cw = w * 32;   // this wave's output-column base
  int h = w;

  if (tid < 256){ lnw_s[tid] = lnw[tid]; lnb_s[tid] = lnb[tid]; bp_s[tid] = bproj[tid]; }
  else if (tid < 384){
    int i = tid - 256;
    ms_s[i] = musig[(((long)b * V_ + (i >> 1)) * T1_ + t) * 2 + (i & 1)];
  }
  __syncthreads();

  // ---- stage x slice with LN applied, as bf16, into Xs ----
  #pragma unroll
  for (int i = 0; i < 4; ++i){
    int seg = i * 512 + tid;          // 2048 segments of 8 elems
    int vr = seg >> 5;
    int c8 = (seg & 31) * 8;
    const float* gp = x + (((long)b * V_ + vr) * T1_ + t) * D_ + c8;
    float4 a0 = *(const float4*)gp;
    float4 a1 = *(const float4*)(gp + 4);
    float mu = ms_s[vr * 2], rs = ms_s[vr * 2 + 1];
    float av[8] = {a0.x, a0.y, a0.z, a0.w, a1.x, a1.y, a1.z, a1.w};
    union { u16 us[8]; uint4 q4; } pk;
    #pragma unroll
    for (int j = 0; j < 8; ++j)
      pk.us[j] = f2bf((av[j] - mu) * rs * lnw_s[c8 + j] + lnb_s[c8 + j]);
    *(uint4*)&Xs[vr * XS + c8] = pk.q4;
  }
  __syncthreads();

  // ---- GEMM1: vf = Xs(64x256) @ Wv^T ; wave w -> cols [32w,32w+32) ----
  f32x4 acc1[4][2];
  #pragma unroll
  for (int mt = 0; mt < 4; ++mt)
    #pragma unroll
    for (int nt = 0; nt < 2; ++nt) acc1[mt][nt] = (f32x4){0.f, 0.f, 0.f, 0.f};
  for (int kk = 0; kk < 8; ++kk){
    short8 af[4], bfr[2];
    #pragma unroll
    for (int mt = 0; mt < 4; ++mt)
      af[mt] = *(const short8*)&Xs[(mt * 16 + lm) * XS + kk * 32 + lq * 8];
    #pragma unroll
    for (int nt = 0; nt < 2; ++nt)
      bfr[nt] = *(const short8*)&wv[(long)(cw + nt * 16 + lm) * D_ + kk * 32 + lq * 8];
    #pragma unroll
    for (int mt = 0; mt < 4; ++mt)
      #pragma unroll
      for (int nt = 0; nt < 2; ++nt)
        acc1[mt][nt] = __builtin_amdgcn_mfma_f32_16x16x32_bf16(af[mt], bfr[nt], acc1[mt][nt], 0, 0, 0);
  }

  // ---- pack acc1 -> bf16 word pairs: pw[mt][nt][p] = rows mt*16+lq*4+2p+{0,1} ----
  unsigned int pw[4][2][2];
  #pragma unroll
  for (int mt = 0; mt < 4; ++mt)
    #pragma unroll
    for (int nt = 0; nt < 2; ++nt)
      #pragma unroll
      for (int p = 0; p < 2; ++p)
        pw[mt][nt][p] = (unsigned int)f2bf(acc1[mt][nt][2*p])
                      | ((unsigned int)f2bf(acc1[mt][nt][2*p+1]) << 16);

  // ---- mix: head h=w: acc2 = attn_h(64x64) @ vf[:, head h]; B-frag built by shuffle ----
  f32x4 acc2[4][2];
  #pragma unroll
  for (int mt = 0; mt < 4; ++mt)
    #pragma unroll
    for (int nt = 0; nt < 2; ++nt) acc2[mt][nt] = (f32x4){0.f, 0.f, 0.f, 0.f};
  #pragma unroll
  for (int kk = 0; kk < 2; ++kk){
    short8 bfrm[2];
    #pragma unroll
    for (int nt = 0; nt < 2; ++nt){
      union { unsigned int wq[4]; short8 s8; } u;
      #pragma unroll
      for (int j2 = 0; j2 < 4; ++j2){
        int srcLane = ((lq & 1) * 2 + (j2 >> 1)) * 16 + lm;
        unsigned int va = __shfl((int)pw[2*kk    ][nt][j2 & 1], srcLane, 64);
        unsigned int vb = __shfl((int)pw[2*kk + 1][nt][j2 & 1], srcLane, 64);
        u.wq[j2] = (lq >= 2) ? vb : va;
      }
      bfrm[nt] = u.s8;
    }
    short8 atf[4];
    #pragma unroll
    for (int mt = 0; mt < 4; ++mt)
      atf[mt] = *(const short8*)&attn[((long)(b * H_ + h) * 64 + mt * 16 + lm) * 64 + kk * 32 + lq * 8];
    #pragma unroll
    for (int mt = 0; mt < 4; ++mt)
      #pragma unroll
      for (int nt = 0; nt < 2; ++nt)
        acc2[mt][nt] = __builtin_amdgcn_mfma_f32_16x16x32_bf16(atf[mt], bfrm[nt], acc2[mt][nt], 0, 0, 0);
  }
  __syncthreads();   // all waves done reading Xs (GEMM1)

  // ---- write mix into Ms (= Xs buffer), row-major; wave w writes cols [32w,32w+32) ----
  #pragma unroll
  for (int mt = 0; mt < 4; ++mt)
    #pragma unroll
    for (int nt = 0; nt < 2; ++nt){
      int col = h * 32 + nt * 16 + lm;
      #pragma unroll
      for (int r = 0; r < 4; ++r){
        int row = mt * 16 + lq * 4 + r;
        Xs[row * XS + col] = f2bf(acc2[mt][nt][r]);
      }
    }
  __syncthreads();

  // ---- GEMM3: out = Ms(64x256) @ Wproj^T ----
  f32x4 acc3[4][2];
  #pragma unroll
  for (int mt = 0; mt < 4; ++mt)
    #pragma unroll
    for (int nt = 0; nt < 2; ++nt) acc3[mt][nt] = (f32x4){0.f, 0.f, 0.f, 0.f};
  for (int kk = 0; kk < 8; ++kk){
    short8 af[4], bfr[2];
    #pragma unroll
    for (int mt = 0; mt < 4; ++mt)
      af[mt] = *(const short8*)&Xs[(mt * 16 + lm) * XS + kk * 32 + lq * 8];
    #pragma unroll
    for (int nt = 0; nt < 2; ++nt)
      bfr[nt] = *(const short8*)&wp[(long)(cw + nt * 16 + lm) * D_ + kk * 32 + lq * 8];
    #pragma unroll
    for (int mt = 0; mt < 4; ++mt)
      #pragma unroll
      for (int nt = 0; nt < 2; ++nt)
        acc3[mt][nt] = __builtin_amdgcn_mfma_f32_16x16x32_bf16(af[mt], bfr[nt], acc3[mt][nt], 0, 0, 0);
  }
  // ---- epilogue: + b_proj + x, store fp32 ----
  #pragma unroll
  for (int mt = 0; mt < 4; ++mt)
    #pragma unroll
    for (int nt = 0; nt < 2; ++nt){
      int e = cw + nt * 16 + lm;
      #pragma unroll
      for (int r = 0; r < 4; ++r){
        int vr = mt * 16 + lq * 4 + r;
        long g = (((long)b * V_ + vr) * T1_ + t) * D_ + e;
        out[g] = acc3[mt][nt][r] + bp_s[e] + x[g];
      }
    }
}

// ---------------- launch ----------------
extern "C" void kernel_launch(void* const* d_in, const int* in_sizes, int n_in,
                              void* d_out, int out_size, void* d_ws, size_t ws_size,
                              hipStream_t stream){
  const float* x     = (const float*)d_in[0];
  const int*   mask  = (const int*)d_in[1];
  const float* lnw   = (const float*)d_in[2];
  const float* lnb   = (const float*)d_in[3];
  const float* wqkv  = (const float*)d_in[4];
  const float* wproj = (const float*)d_in[5];
  const float* bproj = (const float*)d_in[6];
  float* out = (float*)d_out;
  char* ws = (char*)d_ws;
  float* musig = (float*)(ws);              // 263168 f
  float* xsum  = (float*)(ws + 1052672);    // 131072 f
  float* qbuf  = (float*)(ws + 1576960);    // 131072 f
  float* kbuf  = (float*)(ws + 2101248);    // 131072 f
  u16*   attn  = (u16*)  (ws + 2625536);    // 262144 u16
  u16*   wv    = (u16*)  (ws + 3149824);    // 65536 u16
  u16*   wp    = (u16*)  (ws + 3280896);    // 65536 u16

  k1_ln<<<640, 512, 0, stream>>>(x, mask, lnw, lnb, wqkv, wproj, musig, xsum, wv, wp);
  k2a_qk<<<dim3(512, 4), 256, 0, stream>>>(x, mask, lnw, lnb, wqkv, musig, xsum, qbuf, kbuf);
  k2b_attn<<<dim3(64, 4), 256, 0, stream>>>(qbuf, kbuf, attn);
  k3_main<<<B_ * T1_, 512, 0, stream>>>(x, lnw, lnb, bproj, musig, wv, wp, attn, out);
}

// Round 3
// 403.746 us; speedup vs baseline: 1.0056x; 1.0056x over previous
//
#include <hip/hip_runtime.h>
#include <hip/hip_bf16.h>

typedef unsigned short u16;
typedef __attribute__((ext_vector_type(8))) short short8;
typedef __attribute__((ext_vector_type(4))) float f32x4;

#define B_ 8
#define V_ 64
#define T_ 256
#define T1_ 257
#define D_ 256
#define H_ 8
#define DH_ 32

__device__ __forceinline__ u16 f2bf(float f){
  union { float f; unsigned int u; } v; v.f = f;
  unsigned int u = v.u;
  return (u16)((u + 0x7fffu + ((u >> 16) & 1u)) >> 16);
}

// ---------------- kernel 1: LN stats + masked xn-sum + weight conversion ----------------
// grid 640, block 512. Blocks 512..639: convert Wv/Wp to bf16. Blocks 0..511:
// one block per bv, 8 waves; each half-wave owns one t. Block writes xsum
// directly: no atomics, no zeroing pass.
__global__ void k1_ln(const float* __restrict__ x, const int* __restrict__ mask,
                      const float* __restrict__ lnw, const float* __restrict__ lnb,
                      const float* __restrict__ wqkv, const float* __restrict__ wproj,
                      float* __restrict__ musig, float* __restrict__ xsum,
                      u16* __restrict__ wv, u16* __restrict__ wp){
  if (blockIdx.x >= 512){
    int j = (blockIdx.x - 512) * 512 + threadIdx.x;   // 0..65535
    wv[j] = f2bf(wqkv[131072 + j]);
    wp[j] = f2bf(wproj[j]);
    return;
  }
  int bv = blockIdx.x;
  int tid = threadIdx.x;
  int lane = tid & 63, wid = tid >> 6;
  int half = lane >> 5, l32 = lane & 31;
  int c8 = l32 * 8;
  __shared__ float xsred[8][512];
  float4 w0 = *(const float4*)&lnw[c8], w1 = *(const float4*)&lnw[c8 + 4];
  float4 b0 = *(const float4*)&lnb[c8], b1 = *(const float4*)&lnb[c8 + 4];
  float xs[8];
  #pragma unroll
  for (int j = 0; j < 8; ++j) xs[j] = 0.f;
  for (int p = wid; p < 129; p += 8){
    int t = p * 2 + half;
    bool valid = (t < T1_);
    float4 a0 = {0.f,0.f,0.f,0.f}, a1 = {0.f,0.f,0.f,0.f};
    if (valid){
      const float* gp = &x[((long)bv * T1_ + t) * D_ + c8];
      a0 = *(const float4*)gp; a1 = *(const float4*)(gp + 4);
    }
    float s  = a0.x + a0.y + a0.z + a0.w + a1.x + a1.y + a1.z + a1.w;
    float s2 = a0.x*a0.x + a0.y*a0.y + a0.z*a0.z + a0.w*a0.w
             + a1.x*a1.x + a1.y*a1.y + a1.z*a1.z + a1.w*a1.w;
    #pragma unroll
    for (int off = 1; off < 32; off <<= 1){
      s  += __shfl_xor(s,  off, 64);
      s2 += __shfl_xor(s2, off, 64);
    }
    float mu   = s * (1.f / 256.f);
    float var  = s2 * (1.f / 256.f) - mu * mu;
    float rstd = rsqrtf(var + 1e-5f);
    if (valid){
      if (l32 == 0){
        musig[((long)bv * T1_ + t) * 2]     = mu;
        musig[((long)bv * T1_ + t) * 2 + 1] = rstd;
      }
      int m = (t == 0) ? 1 : mask[bv * T_ + (t - 1)];
      if (m){
        xs[0] += (a0.x - mu) * rstd * w0.x + b0.x;
        xs[1] += (a0.y - mu) * rstd * w0.y + b0.y;
        xs[2] += (a0.z - mu) * rstd * w0.z + b0.z;
        xs[3] += (a0.w - mu) * rstd * w0.w + b0.w;
        xs[4] += (a1.x - mu) * rstd * w1.x + b1.x;
        xs[5] += (a1.y - mu) * rstd * w1.y + b1.y;
        xs[6] += (a1.z - mu) * rstd * w1.z + b1.z;
        xs[7] += (a1.w - mu) * rstd * w1.w + b1.w;
      }
    }
  }
  #pragma unroll
  for (int j = 0; j < 8; ++j) xsred[wid][half * 256 + c8 + j] = xs[j];
  __syncthreads();
  if (tid < 256){
    float r = 0.f;
    #pragma unroll
    for (int w2 = 0; w2 < 8; ++w2) r += xsred[w2][tid] + xsred[w2][256 + tid];
    xsum[bv * D_ + tid] = r;
  }
}

// ---------------- kernel 2a: q,k projections (tiny) ----------------
__global__ void k2a_qk(const float* __restrict__ x, const int* __restrict__ mask,
                       const float* __restrict__ lnw, const float* __restrict__ lnb,
                       const float* __restrict__ wqkv,
                       const float* __restrict__ musig, const float* __restrict__ xsum,
                       float* __restrict__ qout, float* __restrict__ kout){
  int bv = blockIdx.x, tid = threadIdx.x;
  int lane = tid & 63, wid = tid >> 6;
  __shared__ __align__(16) float xn0[D_];
  __shared__ __align__(16) float xs[D_];
  __shared__ float redc[4];
  int s = mask[bv * T_ + tid];
  #pragma unroll
  for (int off = 32; off >= 1; off >>= 1) s += __shfl_down(s, off, 64);
  if (lane == 0) redc[wid] = (float)s;
  __syncthreads();
  float cnt = 1.f + redc[0] + redc[1] + redc[2] + redc[3];
  float mu = musig[((long)bv * T1_) * 2], rstd = musig[((long)bv * T1_) * 2 + 1];
  xn0[tid] = (x[((long)bv * T1_) * D_ + tid] - mu) * rstd * lnw[tid] + lnb[tid];
  xs[tid]  = xsum[bv * D_ + tid] * (1.f / cnt);
  __syncthreads();
  float4 xq = *(const float4*)&xn0[lane * 4];
  float4 xk = *(const float4*)&xs[lane * 4];
  int e0 = (blockIdx.y * 4 + wid) * 16;
  for (int i = 0; i < 16; ++i){
    int e = e0 + i;
    float4 wq4 = *(const float4*)&wqkv[(long)e * D_ + lane * 4];
    float4 wk4 = *(const float4*)&wqkv[(long)(256 + e) * D_ + lane * 4];
    float sq = xq.x*wq4.x + xq.y*wq4.y + xq.z*wq4.z + xq.w*wq4.w;
    float sk = xk.x*wk4.x + xk.y*wk4.y + xk.z*wk4.z + xk.w*wk4.w;
    #pragma unroll
    for (int off = 32; off >= 1; off >>= 1){
      sq += __shfl_down(sq, off, 64);
      sk += __shfl_down(sk, off, 64);
    }
    if (lane == 0){ qout[bv * D_ + e] = sq; kout[bv * D_ + e] = sk; }
  }
}

// ---------------- kernel 2b: 64x64 attention per (b,h) ----------------
__global__ void k2b_attn(const float* __restrict__ q, const float* __restrict__ k,
                         u16* __restrict__ attn){
  int bh = blockIdx.x; int b = bh >> 3, h = bh & 7;
  int tid = threadIdx.x;
  int lane = tid & 63, wid = tid >> 6;
  __shared__ float qs[64][33], ks[64][33];
  #pragma unroll
  for (int j = 0; j < 2; ++j){
    int i4 = tid * 2 + j;
    int r = i4 >> 3, c4 = (i4 & 7) * 4;
    float4 vq = *(const float4*)&q[((long)(b * V_ + r)) * D_ + h * DH_ + c4];
    float4 vk = *(const float4*)&k[((long)(b * V_ + r)) * D_ + h * DH_ + c4];
    qs[r][c4] = vq.x; qs[r][c4+1] = vq.y; qs[r][c4+2] = vq.z; qs[r][c4+3] = vq.w;
    ks[r][c4] = vk.x; ks[r][c4+1] = vk.y; ks[r][c4+2] = vk.z; ks[r][c4+3] = vk.w;
  }
  __syncthreads();
  const float scale = 0.17677669529663687f;  // 1/sqrt(32)
  for (int i = blockIdx.y * 4; i < blockIdx.y * 4 + 4; ++i){
    int qr = i * 4 + wid;
    float a = 0.f;
    #pragma unroll
    for (int d = 0; d < DH_; ++d) a += qs[qr][d] * ks[lane][d];
    a *= scale;
    float mx = a;
    #pragma unroll
    for (int off = 1; off < 64; off <<= 1) mx = fmaxf(mx, __shfl_xor(mx, off, 64));
    float e = __expf(a - mx);
    float sum = e;
    #pragma unroll
    for (int off = 1; off < 64; off <<= 1) sum += __shfl_xor(sum, off, 64);
    attn[((long)bh * 64 + qr) * 64 + lane] = f2bf(e * (1.f / sum));
  }
}

// ---------------- kernel 3: fused LN -> V-proj -> attn-mix -> out-proj -> residual ----------------
// r0 dataflow (mix B-operand via LDS, no shuffles) at r2 LDS footprint:
// VT is wave-private (wave w's GEMM1 output == its own head's mix B-operand),
// so after a barrier confirming all GEMM1 A-reads, each wave stores its 4 KB
// VT block into the then-dead Xs buffer (XOR-swizzled, 16B aligned) and reads
// it back without any cross-wave sync. LDS ~37 KB -> 3 blocks/CU.
__global__ __launch_bounds__(512, 6) void k3_main(
    const float* __restrict__ x, const float* __restrict__ lnw, const float* __restrict__ lnb,
    const float* __restrict__ bproj, const float* __restrict__ musig,
    const u16* __restrict__ wv, const u16* __restrict__ wp,
    const u16* __restrict__ attn, float* __restrict__ out){
  constexpr int XS = 264;   // row stride (bf16 elems) for Xs/Ms
  __shared__ __align__(16) u16 Xs[64 * XS];    // xn slice; then VT scratch; then Ms
  __shared__ float lnw_s[D_], lnb_s[D_], bp_s[D_];
  __shared__ float ms_s[V_ * 2];

  int bt = blockIdx.x; int b = bt / T1_, t = bt % T1_;
  int tid = threadIdx.x;
  int w = tid >> 6, lane = tid & 63, lm = lane & 15, lq = lane >> 4;
  int cw = w * 32;   // this wave's output-column base
  int h = w;

  if (tid < 256){ lnw_s[tid] = lnw[tid]; lnb_s[tid] = lnb[tid]; bp_s[tid] = bproj[tid]; }
  else if (tid < 384){
    int i = tid - 256;
    ms_s[i] = musig[(((long)b * V_ + (i >> 1)) * T1_ + t) * 2 + (i & 1)];
  }
  __syncthreads();

  // ---- stage x slice with LN applied, as bf16, into Xs ----
  #pragma unroll
  for (int i = 0; i < 4; ++i){
    int seg = i * 512 + tid;          // 2048 segments of 8 elems
    int vr = seg >> 5;
    int c8 = (seg & 31) * 8;
    const float* gp = x + (((long)b * V_ + vr) * T1_ + t) * D_ + c8;
    float4 a0 = *(const float4*)gp;
    float4 a1 = *(const float4*)(gp + 4);
    float mu = ms_s[vr * 2], rs = ms_s[vr * 2 + 1];
    float av[8] = {a0.x, a0.y, a0.z, a0.w, a1.x, a1.y, a1.z, a1.w};
    union { u16 us[8]; uint4 q4; } pk;
    #pragma unroll
    for (int j = 0; j < 8; ++j)
      pk.us[j] = f2bf((av[j] - mu) * rs * lnw_s[c8 + j] + lnb_s[c8 + j]);
    *(uint4*)&Xs[vr * XS + c8] = pk.q4;
  }
  __syncthreads();   // bar1: Xs complete

  // ---- GEMM1: vf = Xs(64x256) @ Wv^T ; wave w -> cols [32w,32w+32) ----
  f32x4 acc1[4][2];
  #pragma unroll
  for (int mt = 0; mt < 4; ++mt)
    #pragma unroll
    for (int nt = 0; nt < 2; ++nt) acc1[mt][nt] = (f32x4){0.f, 0.f, 0.f, 0.f};
  for (int kk = 0; kk < 8; ++kk){
    short8 af[4], bfr[2];
    #pragma unroll
    for (int mt = 0; mt < 4; ++mt)
      af[mt] = *(const short8*)&Xs[(mt * 16 + lm) * XS + kk * 32 + lq * 8];
    #pragma unroll
    for (int nt = 0; nt < 2; ++nt)
      bfr[nt] = *(const short8*)&wv[(long)(cw + nt * 16 + lm) * D_ + kk * 32 + lq * 8];
    #pragma unroll
    for (int mt = 0; mt < 4; ++mt)
      #pragma unroll
      for (int nt = 0; nt < 2; ++nt)
        acc1[mt][nt] = __builtin_amdgcn_mfma_f32_16x16x32_bf16(af[mt], bfr[nt], acc1[mt][nt], 0, 0, 0);
  }
  __syncthreads();   // bar2: all GEMM1 A-reads of Xs done -> Xs reusable as VT

  // ---- VT (wave-private, inside Xs): [32 local cols][64 vars], XOR-swizzled ----
  // elem offset within wave block: c*64 + ((v8 ^ (c&7))*8) + (v&7), v8 = v>>3.
  u16* vtw = &Xs[w * 2048];
  #pragma unroll
  for (int mt = 0; mt < 4; ++mt)
    #pragma unroll
    for (int nt = 0; nt < 2; ++nt){
      int c  = nt * 16 + lm;                 // local col
      int v8 = mt * 2 + (lq >> 1);           // var group (vars mt*16+lq*4 .. +3)
      int off = c * 64 + ((v8 ^ (lm & 7)) * 8) + (lq & 1) * 4;
      union { u16 us[4]; uint2 q2; } pv;
      #pragma unroll
      for (int r = 0; r < 4; ++r) pv.us[r] = f2bf(acc1[mt][nt][r]);
      *(uint2*)&vtw[off] = pv.q2;
    }

  // ---- mix: head h=w: acc2 = attn_h(64x64) @ vf[:, head h] (own VT, no barrier) ----
  f32x4 acc2[4][2];
  #pragma unroll
  for (int mt = 0; mt < 4; ++mt)
    #pragma unroll
    for (int nt = 0; nt < 2; ++nt) acc2[mt][nt] = (f32x4){0.f, 0.f, 0.f, 0.f};
  #pragma unroll
  for (int kk = 0; kk < 2; ++kk){
    short8 atf[4], bfr[2];
    #pragma unroll
    for (int mt = 0; mt < 4; ++mt)
      atf[mt] = *(const short8*)&attn[((long)(b * H_ + h) * 64 + mt * 16 + lm) * 64 + kk * 32 + lq * 8];
    #pragma unroll
    for (int nt = 0; nt < 2; ++nt){
      int c = nt * 16 + lm;
      int v8 = kk * 4 + lq;                  // vars kk*32+lq*8 .. +7
      bfr[nt] = *(const short8*)&vtw[c * 64 + ((v8 ^ (lm & 7)) * 8)];
    }
    #pragma unroll
    for (int mt = 0; mt < 4; ++mt)
      #pragma unroll
      for (int nt = 0; nt < 2; ++nt)
        acc2[mt][nt] = __builtin_amdgcn_mfma_f32_16x16x32_bf16(atf[mt], bfr[nt], acc2[mt][nt], 0, 0, 0);
  }
  __syncthreads();   // bar3: all waves done reading their VT -> Xs reusable as Ms

  // ---- write mix into Ms (= Xs buffer), row-major; wave w writes cols [32w,32w+32) ----
  #pragma unroll
  for (int mt = 0; mt < 4; ++mt)
    #pragma unroll
    for (int nt = 0; nt < 2; ++nt){
      int col = h * 32 + nt * 16 + lm;
      #pragma unroll
      for (int r = 0; r < 4; ++r){
        int row = mt * 16 + lq * 4 + r;
        Xs[row * XS + col] = f2bf(acc2[mt][nt][r]);
      }
    }
  __syncthreads();   // bar4: Ms complete

  // ---- GEMM3: out = Ms(64x256) @ Wproj^T ----
  f32x4 acc3[4][2];
  #pragma unroll
  for (int mt = 0; mt < 4; ++mt)
    #pragma unroll
    for (int nt = 0; nt < 2; ++nt) acc3[mt][nt] = (f32x4){0.f, 0.f, 0.f, 0.f};
  for (int kk = 0; kk < 8; ++kk){
    short8 af[4], bfr[2];
    #pragma unroll
    for (int mt = 0; mt < 4; ++mt)
      af[mt] = *(const short8*)&Xs[(mt * 16 + lm) * XS + kk * 32 + lq * 8];
    #pragma unroll
    for (int nt = 0; nt < 2; ++nt)
      bfr[nt] = *(const short8*)&wp[(long)(cw + nt * 16 + lm) * D_ + kk * 32 + lq * 8];
    #pragma unroll
    for (int mt = 0; mt < 4; ++mt)
      #pragma unroll
      for (int nt = 0; nt < 2; ++nt)
        acc3[mt][nt] = __builtin_amdgcn_mfma_f32_16x16x32_bf16(af[mt], bfr[nt], acc3[mt][nt], 0, 0, 0);
  }
  // ---- epilogue: + b_proj + x, store fp32 ----
  #pragma unroll
  for (int mt = 0; mt < 4; ++mt)
    #pragma unroll
    for (int nt = 0; nt < 2; ++nt){
      int e = cw + nt * 16 + lm;
      #pragma unroll
      for (int r = 0; r < 4; ++r){
        int vr = mt * 16 + lq * 4 + r;
        long g = (((long)b * V_ + vr) * T1_ + t) * D_ + e;
        out[g] = acc3[mt][nt][r] + bp_s[e] + x[g];
      }
    }
}

// ---------------- launch ----------------
extern "C" void kernel_launch(void* const* d_in, const int* in_sizes, int n_in,
                              void* d_out, int out_size, void* d_ws, size_t ws_size,
                              hipStream_t stream){
  const float* x     = (const float*)d_in[0];
  const int*   mask  = (const int*)d_in[1];
  const float* lnw   = (const float*)d_in[2];
  const float* lnb   = (const float*)d_in[3];
  const float* wqkv  = (const float*)d_in[4];
  const float* wproj = (const float*)d_in[5];
  const float* bproj = (const float*)d_in[6];
  float* out = (float*)d_out;
  char* ws = (char*)d_ws;
  float* musig = (float*)(ws);              // 263168 f
  float* xsum  = (float*)(ws + 1052672);    // 131072 f
  float* qbuf  = (float*)(ws + 1576960);    // 131072 f
  float* kbuf  = (float*)(ws + 2101248);    // 131072 f
  u16*   attn  = (u16*)  (ws + 2625536);    // 262144 u16
  u16*   wv    = (u16*)  (ws + 3149824);    // 65536 u16
  u16*   wp    = (u16*)  (ws + 3280896);    // 65536 u16

  k1_ln<<<640, 512, 0, stream>>>(x, mask, lnw, lnb, wqkv, wproj, musig, xsum, wv, wp);
  k2a_qk<<<dim3(512, 4), 256, 0, stream>>>(x, mask, lnw, lnb, wqkv, musig, xsum, qbuf, kbuf);
  k2b_attn<<<dim3(64, 4), 256, 0, stream>>>(qbuf, kbuf, attn);
  k3_main<<<B_ * T1_, 512, 0, stream>>>(x, lnw, lnb, bproj, musig, wv, wp, attn, out);
}

// Round 4
// 391.557 us; speedup vs baseline: 1.0369x; 1.0311x over previous
//
#include <hip/hip_runtime.h>
#include <hip/hip_bf16.h>

typedef unsigned short u16;
typedef __attribute__((ext_vector_type(8))) short short8;
typedef __attribute__((ext_vector_type(4))) float f32x4;

#define B_ 8
#define V_ 64
#define T_ 256
#define T1_ 257
#define D_ 256
#define H_ 8
#define DH_ 32

__device__ __forceinline__ u16 f2bf(float f){
  union { float f; unsigned int u; } v; v.f = f;
  unsigned int u = v.u;
  return (u16)((u + 0x7fffu + ((u >> 16) & 1u)) >> 16);
}

// ---------------- kernel 1: LN stats + masked xn-sum + weight conversion ----------------
// grid 640, block 512. Blocks 512..639: convert Wv/Wp to bf16. Blocks 0..511:
// one block per bv, 8 waves; each half-wave owns one t. Block writes xsum
// directly: no atomics, no zeroing pass.
__global__ void k1_ln(const float* __restrict__ x, const int* __restrict__ mask,
                      const float* __restrict__ lnw, const float* __restrict__ lnb,
                      const float* __restrict__ wqkv, const float* __restrict__ wproj,
                      float* __restrict__ musig, float* __restrict__ xsum,
                      u16* __restrict__ wv, u16* __restrict__ wp){
  if (blockIdx.x >= 512){
    int j = (blockIdx.x - 512) * 512 + threadIdx.x;   // 0..65535
    wv[j] = f2bf(wqkv[131072 + j]);
    wp[j] = f2bf(wproj[j]);
    return;
  }
  int bv = blockIdx.x;
  int tid = threadIdx.x;
  int lane = tid & 63, wid = tid >> 6;
  int half = lane >> 5, l32 = lane & 31;
  int c8 = l32 * 8;
  __shared__ float xsred[8][512];
  float4 w0 = *(const float4*)&lnw[c8], w1 = *(const float4*)&lnw[c8 + 4];
  float4 b0 = *(const float4*)&lnb[c8], b1 = *(const float4*)&lnb[c8 + 4];
  float xs[8];
  #pragma unroll
  for (int j = 0; j < 8; ++j) xs[j] = 0.f;
  for (int p = wid; p < 129; p += 8){
    int t = p * 2 + half;
    bool valid = (t < T1_);
    float4 a0 = {0.f,0.f,0.f,0.f}, a1 = {0.f,0.f,0.f,0.f};
    if (valid){
      const float* gp = &x[((long)bv * T1_ + t) * D_ + c8];
      a0 = *(const float4*)gp; a1 = *(const float4*)(gp + 4);
    }
    float s  = a0.x + a0.y + a0.z + a0.w + a1.x + a1.y + a1.z + a1.w;
    float s2 = a0.x*a0.x + a0.y*a0.y + a0.z*a0.z + a0.w*a0.w
             + a1.x*a1.x + a1.y*a1.y + a1.z*a1.z + a1.w*a1.w;
    #pragma unroll
    for (int off = 1; off < 32; off <<= 1){
      s  += __shfl_xor(s,  off, 64);
      s2 += __shfl_xor(s2, off, 64);
    }
    float mu   = s * (1.f / 256.f);
    float var  = s2 * (1.f / 256.f) - mu * mu;
    float rstd = rsqrtf(var + 1e-5f);
    if (valid){
      if (l32 == 0){
        musig[((long)bv * T1_ + t) * 2]     = mu;
        musig[((long)bv * T1_ + t) * 2 + 1] = rstd;
      }
      int m = (t == 0) ? 1 : mask[bv * T_ + (t - 1)];
      if (m){
        xs[0] += (a0.x - mu) * rstd * w0.x + b0.x;
        xs[1] += (a0.y - mu) * rstd * w0.y + b0.y;
        xs[2] += (a0.z - mu) * rstd * w0.z + b0.z;
        xs[3] += (a0.w - mu) * rstd * w0.w + b0.w;
        xs[4] += (a1.x - mu) * rstd * w1.x + b1.x;
        xs[5] += (a1.y - mu) * rstd * w1.y + b1.y;
        xs[6] += (a1.z - mu) * rstd * w1.z + b1.z;
        xs[7] += (a1.w - mu) * rstd * w1.w + b1.w;
      }
    }
  }
  #pragma unroll
  for (int j = 0; j < 8; ++j) xsred[wid][half * 256 + c8 + j] = xs[j];
  __syncthreads();
  if (tid < 256){
    float r = 0.f;
    #pragma unroll
    for (int w2 = 0; w2 < 8; ++w2) r += xsred[w2][tid] + xsred[w2][256 + tid];
    xsum[bv * D_ + tid] = r;
  }
}

// ---------------- kernel 2a: q,k projections (tiny) ----------------
__global__ void k2a_qk(const float* __restrict__ x, const int* __restrict__ mask,
                       const float* __restrict__ lnw, const float* __restrict__ lnb,
                       const float* __restrict__ wqkv,
                       const float* __restrict__ musig, const float* __restrict__ xsum,
                       float* __restrict__ qout, float* __restrict__ kout){
  int bv = blockIdx.x, tid = threadIdx.x;
  int lane = tid & 63, wid = tid >> 6;
  __shared__ __align__(16) float xn0[D_];
  __shared__ __align__(16) float xs[D_];
  __shared__ float redc[4];
  int s = mask[bv * T_ + tid];
  #pragma unroll
  for (int off = 32; off >= 1; off >>= 1) s += __shfl_down(s, off, 64);
  if (lane == 0) redc[wid] = (float)s;
  __syncthreads();
  float cnt = 1.f + redc[0] + redc[1] + redc[2] + redc[3];
  float mu = musig[((long)bv * T1_) * 2], rstd = musig[((long)bv * T1_) * 2 + 1];
  xn0[tid] = (x[((long)bv * T1_) * D_ + tid] - mu) * rstd * lnw[tid] + lnb[tid];
  xs[tid]  = xsum[bv * D_ + tid] * (1.f / cnt);
  __syncthreads();
  float4 xq = *(const float4*)&xn0[lane * 4];
  float4 xk = *(const float4*)&xs[lane * 4];
  int e0 = (blockIdx.y * 4 + wid) * 16;
  for (int i = 0; i < 16; ++i){
    int e = e0 + i;
    float4 wq4 = *(const float4*)&wqkv[(long)e * D_ + lane * 4];
    float4 wk4 = *(const float4*)&wqkv[(long)(256 + e) * D_ + lane * 4];
    float sq = xq.x*wq4.x + xq.y*wq4.y + xq.z*wq4.z + xq.w*wq4.w;
    float sk = xk.x*wk4.x + xk.y*wk4.y + xk.z*wk4.z + xk.w*wk4.w;
    #pragma unroll
    for (int off = 32; off >= 1; off >>= 1){
      sq += __shfl_down(sq, off, 64);
      sk += __shfl_down(sk, off, 64);
    }
    if (lane == 0){ qout[bv * D_ + e] = sq; kout[bv * D_ + e] = sk; }
  }
}

// ---------------- kernel 2b: 64x64 attention per (b,h) ----------------
__global__ void k2b_attn(const float* __restrict__ q, const float* __restrict__ k,
                         u16* __restrict__ attn){
  int bh = blockIdx.x; int b = bh >> 3, h = bh & 7;
  int tid = threadIdx.x;
  int lane = tid & 63, wid = tid >> 6;
  __shared__ float qs[64][33], ks[64][33];
  #pragma unroll
  for (int j = 0; j < 2; ++j){
    int i4 = tid * 2 + j;
    int r = i4 >> 3, c4 = (i4 & 7) * 4;
    float4 vq = *(const float4*)&q[((long)(b * V_ + r)) * D_ + h * DH_ + c4];
    float4 vk = *(const float4*)&k[((long)(b * V_ + r)) * D_ + h * DH_ + c4];
    qs[r][c4] = vq.x; qs[r][c4+1] = vq.y; qs[r][c4+2] = vq.z; qs[r][c4+3] = vq.w;
    ks[r][c4] = vk.x; ks[r][c4+1] = vk.y; ks[r][c4+2] = vk.z; ks[r][c4+3] = vk.w;
  }
  __syncthreads();
  const float scale = 0.17677669529663687f;  // 1/sqrt(32)
  for (int i = blockIdx.y * 4; i < blockIdx.y * 4 + 4; ++i){
    int qr = i * 4 + wid;
    float a = 0.f;
    #pragma unroll
    for (int d = 0; d < DH_; ++d) a += qs[qr][d] * ks[lane][d];
    a *= scale;
    float mx = a;
    #pragma unroll
    for (int off = 1; off < 64; off <<= 1) mx = fmaxf(mx, __shfl_xor(mx, off, 64));
    float e = __expf(a - mx);
    float sum = e;
    #pragma unroll
    for (int off = 1; off < 64; off <<= 1) sum += __shfl_xor(sum, off, 64);
    attn[((long)bh * 64 + qr) * 64 + lane] = f2bf(e * (1.f / sum));
  }
}

// ---------------- kernel 3: fused block, TWO t's per block ----------------
// grid B*129 (1032), block 512 (8 waves). Block handles t0=2*ty and t0+1:
// wv/wp/attn fragments loaded ONCE feed both t-slices (2x MFMA per loaded
// B-fragment, half the barrier stalls & L2 weight traffic per unit work).
// Xs holds both slices (67.6 KB); VT is wave-private in dead Xs (r3 scheme).
// launch_bounds(512,4): the allocation regime with the clean (no-spill)
// WRITE_SIZE profile. acc1 packed to bf16 pairs before bar2 to halve its
// live range.
__global__ __launch_bounds__(512, 4) void k3_main(
    const float* __restrict__ x, const float* __restrict__ lnw, const float* __restrict__ lnb,
    const float* __restrict__ bproj, const float* __restrict__ musig,
    const u16* __restrict__ wv, const u16* __restrict__ wp,
    const u16* __restrict__ attn, float* __restrict__ out){
  constexpr int XS = 264;            // row stride (bf16 elems)
  constexpr int TSL = 64 * XS;       // 16896 elems per t-slice
  __shared__ __align__(16) u16 Xs[2 * TSL];     // both xn slices; VT scratch; Ms
  __shared__ float lnw_s[D_], lnb_s[D_], bp_s[D_];
  __shared__ float ms_s[2][V_][2];

  int bt = blockIdx.x; int b = bt / 129, ty = bt % 129;
  int t0 = ty * 2;
  int tid = threadIdx.x;
  int w = tid >> 6, lane = tid & 63, lm = lane & 15, lq = lane >> 4;
  int cw = w * 32;
  int h = w;

  if (tid < 256){ lnw_s[tid] = lnw[tid]; lnb_s[tid] = lnb[tid]; bp_s[tid] = bproj[tid]; }
  else {
    int i = tid - 256;                 // 0..255
    int tslot = i >> 7, vr = (i >> 1) & 63, sel = i & 1;
    int t = t0 + tslot; if (t > 256) t = 256;   // clamp (ty=128 dual-slot)
    ms_s[tslot][vr][sel] = musig[(((long)b * V_ + vr) * T1_ + t) * 2 + sel];
  }
  __syncthreads();

  // ---- stage both x slices with LN applied, bf16, into Xs ----
  #pragma unroll
  for (int i = 0; i < 8; ++i){
    int seg = i * 512 + tid;           // 4096 segments of 8 elems
    int vr2 = seg >> 5;                // 0..127
    int tslot = vr2 >> 6, vr = vr2 & 63;
    int c8 = (seg & 31) * 8;
    int t = t0 + tslot;
    float4 a0 = {0.f,0.f,0.f,0.f}, a1 = {0.f,0.f,0.f,0.f};
    if (t < T1_){
      const float* gp = x + (((long)b * V_ + vr) * T1_ + t) * D_ + c8;
      a0 = *(const float4*)gp;
      a1 = *(const float4*)(gp + 4);
    }
    float mu = ms_s[tslot][vr][0], rs = ms_s[tslot][vr][1];
    float av[8] = {a0.x, a0.y, a0.z, a0.w, a1.x, a1.y, a1.z, a1.w};
    union { u16 us[8]; uint4 q4; } pk;
    #pragma unroll
    for (int j = 0; j < 8; ++j)
      pk.us[j] = f2bf((av[j] - mu) * rs * lnw_s[c8 + j] + lnb_s[c8 + j]);
    *(uint4*)&Xs[tslot * TSL + vr * XS + c8] = pk.q4;
  }
  __syncthreads();   // bar1: Xs complete

  // ---- GEMM1 (both slices): vf = Xs @ Wv^T ; wv fragment loaded once ----
  f32x4 acc1[2][4][2];
  #pragma unroll
  for (int tt = 0; tt < 2; ++tt)
    #pragma unroll
    for (int mt = 0; mt < 4; ++mt)
      #pragma unroll
      for (int nt = 0; nt < 2; ++nt) acc1[tt][mt][nt] = (f32x4){0.f, 0.f, 0.f, 0.f};
  for (int kk = 0; kk < 8; ++kk){
    short8 bfr[2];
    #pragma unroll
    for (int nt = 0; nt < 2; ++nt)
      bfr[nt] = *(const short8*)&wv[(long)(cw + nt * 16 + lm) * D_ + kk * 32 + lq * 8];
    #pragma unroll
    for (int tt = 0; tt < 2; ++tt){
      short8 af[4];
      #pragma unroll
      for (int mt = 0; mt < 4; ++mt)
        af[mt] = *(const short8*)&Xs[tt * TSL + (mt * 16 + lm) * XS + kk * 32 + lq * 8];
      #pragma unroll
      for (int mt = 0; mt < 4; ++mt)
        #pragma unroll
        for (int nt = 0; nt < 2; ++nt)
          acc1[tt][mt][nt] = __builtin_amdgcn_mfma_f32_16x16x32_bf16(af[mt], bfr[nt], acc1[tt][mt][nt], 0, 0, 0);
    }
  }
  // pack acc1 -> bf16 word pairs (halves live state across bar2)
  unsigned int pw[2][4][2][2];
  #pragma unroll
  for (int tt = 0; tt < 2; ++tt)
    #pragma unroll
    for (int mt = 0; mt < 4; ++mt)
      #pragma unroll
      for (int nt = 0; nt < 2; ++nt)
        #pragma unroll
        for (int p = 0; p < 2; ++p)
          pw[tt][mt][nt][p] = (unsigned int)f2bf(acc1[tt][mt][nt][2*p])
                            | ((unsigned int)f2bf(acc1[tt][mt][nt][2*p+1]) << 16);
  __syncthreads();   // bar2: all GEMM1 A-reads done -> Xs reusable as VT scratch

  // ---- VT (wave-private, in dead Xs): per tt, [32 cols][64 vars], XOR-swizzled ----
  u16* vtw = &Xs[w * 4224];            // 8.25 KB/wave region; we use 8 KB
  #pragma unroll
  for (int tt = 0; tt < 2; ++tt)
    #pragma unroll
    for (int mt = 0; mt < 4; ++mt)
      #pragma unroll
      for (int nt = 0; nt < 2; ++nt){
        int c  = nt * 16 + lm;
        int v8 = mt * 2 + (lq >> 1);
        int off = tt * 2048 + c * 64 + ((v8 ^ (lm & 7)) * 8) + (lq & 1) * 4;
        union { unsigned int wq[2]; uint2 q2; } pv;
        pv.wq[0] = pw[tt][mt][nt][0]; pv.wq[1] = pw[tt][mt][nt][1];
        *(uint2*)&vtw[off] = pv.q2;
      }

  // ---- mix (both slices): acc2 = attn_h @ vf ; attn fragments loaded once ----
  short8 atf[2][4];
  #pragma unroll
  for (int kk = 0; kk < 2; ++kk)
    #pragma unroll
    for (int mt = 0; mt < 4; ++mt)
      atf[kk][mt] = *(const short8*)&attn[((long)(b * H_ + h) * 64 + mt * 16 + lm) * 64 + kk * 32 + lq * 8];
  f32x4 acc2[2][4][2];
  #pragma unroll
  for (int tt = 0; tt < 2; ++tt)
    #pragma unroll
    for (int mt = 0; mt < 4; ++mt)
      #pragma unroll
      for (int nt = 0; nt < 2; ++nt) acc2[tt][mt][nt] = (f32x4){0.f, 0.f, 0.f, 0.f};
  #pragma unroll
  for (int kk = 0; kk < 2; ++kk)
    #pragma unroll
    for (int tt = 0; tt < 2; ++tt){
      short8 bfr[2];
      #pragma unroll
      for (int nt = 0; nt < 2; ++nt){
        int c = nt * 16 + lm;
        int v8 = kk * 4 + lq;
        bfr[nt] = *(const short8*)&vtw[tt * 2048 + c * 64 + ((v8 ^ (lm & 7)) * 8)];
      }
      #pragma unroll
      for (int mt = 0; mt < 4; ++mt)
        #pragma unroll
        for (int nt = 0; nt < 2; ++nt)
          acc2[tt][mt][nt] = __builtin_amdgcn_mfma_f32_16x16x32_bf16(atf[kk][mt], bfr[nt], acc2[tt][mt][nt], 0, 0, 0);
    }
  __syncthreads();   // bar3: all VT reads done -> Xs reusable as Ms

  // ---- write mix into Ms (= Xs), row-major; wave w -> cols [32w,32w+32) ----
  #pragma unroll
  for (int tt = 0; tt < 2; ++tt)
    #pragma unroll
    for (int mt = 0; mt < 4; ++mt)
      #pragma unroll
      for (int nt = 0; nt < 2; ++nt){
        int col = h * 32 + nt * 16 + lm;
        #pragma unroll
        for (int r = 0; r < 4; ++r){
          int row = mt * 16 + lq * 4 + r;
          Xs[tt * TSL + row * XS + col] = f2bf(acc2[tt][mt][nt][r]);
        }
      }
  __syncthreads();   // bar4: Ms complete

  // ---- GEMM3 (both slices): out = Ms @ Wproj^T ; wp fragment loaded once ----
  f32x4 acc3[2][4][2];
  #pragma unroll
  for (int tt = 0; tt < 2; ++tt)
    #pragma unroll
    for (int mt = 0; mt < 4; ++mt)
      #pragma unroll
      for (int nt = 0; nt < 2; ++nt) acc3[tt][mt][nt] = (f32x4){0.f, 0.f, 0.f, 0.f};
  for (int kk = 0; kk < 8; ++kk){
    short8 bfr[2];
    #pragma unroll
    for (int nt = 0; nt < 2; ++nt)
      bfr[nt] = *(const short8*)&wp[(long)(cw + nt * 16 + lm) * D_ + kk * 32 + lq * 8];
    #pragma unroll
    for (int tt = 0; tt < 2; ++tt){
      short8 af[4];
      #pragma unroll
      for (int mt = 0; mt < 4; ++mt)
        af[mt] = *(const short8*)&Xs[tt * TSL + (mt * 16 + lm) * XS + kk * 32 + lq * 8];
      #pragma unroll
      for (int mt = 0; mt < 4; ++mt)
        #pragma unroll
        for (int nt = 0; nt < 2; ++nt)
          acc3[tt][mt][nt] = __builtin_amdgcn_mfma_f32_16x16x32_bf16(af[mt], bfr[nt], acc3[tt][mt][nt], 0, 0, 0);
    }
  }
  // ---- epilogue: + b_proj + x, store fp32 (guard t validity) ----
  #pragma unroll
  for (int tt = 0; tt < 2; ++tt){
    int t = t0 + tt;
    if (t < T1_){
      #pragma unroll
      for (int mt = 0; mt < 4; ++mt)
        #pragma unroll
        for (int nt = 0; nt < 2; ++nt){
          int e = cw + nt * 16 + lm;
          #pragma unroll
          for (int r = 0; r < 4; ++r){
            int vr = mt * 16 + lq * 4 + r;
            long g = (((long)b * V_ + vr) * T1_ + t) * D_ + e;
            out[g] = acc3[tt][mt][nt][r] + bp_s[e] + x[g];
          }
        }
    }
  }
}

// ---------------- launch ----------------
extern "C" void kernel_launch(void* const* d_in, const int* in_sizes, int n_in,
                              void* d_out, int out_size, void* d_ws, size_t ws_size,
                              hipStream_t stream){
  const float* x     = (const float*)d_in[0];
  const int*   mask  = (const int*)d_in[1];
  const float* lnw   = (const float*)d_in[2];
  const float* lnb   = (const float*)d_in[3];
  const float* wqkv  = (const float*)d_in[4];
  const float* wproj = (const float*)d_in[5];
  const float* bproj = (const float*)d_in[6];
  float* out = (float*)d_out;
  char* ws = (char*)d_ws;
  float* musig = (float*)(ws);              // 263168 f
  float* xsum  = (float*)(ws + 1052672);    // 131072 f
  float* qbuf  = (float*)(ws + 1576960);    // 131072 f
  float* kbuf  = (float*)(ws + 2101248);    // 131072 f
  u16*   attn  = (u16*)  (ws + 2625536);    // 262144 u16
  u16*   wv    = (u16*)  (ws + 3149824);    // 65536 u16
  u16*   wp    = (u16*)  (ws + 3280896);    // 65536 u16

  k1_ln<<<640, 512, 0, stream>>>(x, mask, lnw, lnb, wqkv, wproj, musig, xsum, wv, wp);
  k2a_qk<<<dim3(512, 4), 256, 0, stream>>>(x, mask, lnw, lnb, wqkv, musig, xsum, qbuf, kbuf);
  k2b_attn<<<dim3(64, 4), 256, 0, stream>>>(qbuf, kbuf, attn);
  k3_main<<<B_ * 129, 512, 0, stream>>>(x, lnw, lnb, bproj, musig, wv, wp, attn, out);
}